// Round 5
// baseline (328.007 us; speedup 1.0000x reference)
//
#include <hip/hip_runtime.h>
#include <hip/hip_bf16.h>
#include <stdint.h>

// T=1 => softmax over size-1 axis == 1 => attention output == V; q/k/RoPE dead.
// Pipeline: zero(G,U) -> router -> top-128 -> rms1 (V=bv, X1=x, Hb) ->
// V += Hb@wv -> X1 += V@wo -> rms2 -> G += H2b@Wg -> U += H2b@Wu ->
// Mb=silu(G)*U + out copy/scatter -> out[sel] += Mb@Wd.
//
// GEMM (round-6, resubmitted round-7: round-4 bench was an infra failure --
// "container failed twice", no counters; source re-audited for hang/crash
// hazards and resubmitted unchanged). GRANULE fix: rounds 0-3 all pinned at
// 1.4-1.6 TB/s across three pipeline structures and 20-35% occupancy -> not
// latency, not barriers: the common factor was B fetched as 128B chunks
// strided by the 8-22KB row pitch (32-col tile). Round-1's 64B granule got
// 840 GB/s; 128B gets ~1.5 TB/s -> BW tracks contiguous-chunk size.
// Fix: tile 64(M)x128(N), BK=32 -> one staging instruction = 64 lanes x 4B
// = 256B contiguous; block covers full 512B row-spans.
// Col-per-thread staging keeps [n][k] LDS + b128 frag reads. M-split x2
// (pair shares B chunk, same XCD via swizzle). DUAL dropped (wg/wu = two
// launches; A is L2-resident). Raw-barrier counted-vmcnt stage + depth-2
// register prefetch retained from round-3 (correct, neutral-cost).

#define D_ 2048
#define I_ 5504
#define NROWS 256
#define KSEL 128

typedef __attribute__((ext_vector_type(8))) short short8;   // 8 x bf16
typedef __attribute__((ext_vector_type(4))) float floatx4;  // MFMA acc

__device__ __forceinline__ unsigned int pk2(float lo, float hi) {
  __hip_bfloat162 h = __float22bfloat162_rn(float2{lo, hi});  // v_cvt_pk_bf16_f32
  unsigned int u; __builtin_memcpy(&u, &h, 4); return u;
}

// ---------------- K0: zero G,U (contiguous 5636096 B) ----------------
__global__ void k_zero(float4* __restrict__ p, int n4) {
  int i = blockIdx.x * 256 + threadIdx.x;
  int st = gridDim.x * 256;
  for (; i < n4; i += st) p[i] = float4{0.f, 0.f, 0.f, 0.f};
}

// ---------------- K1: router scores ----------------
__global__ void k_router(const float* __restrict__ hid, const float* __restrict__ rw,
                         const float* __restrict__ rb, float* __restrict__ scores) {
  int b = blockIdx.x, t = threadIdx.x;
  const float4* x4 = (const float4*)(hid + (size_t)b * D_);
  const float4* w4 = (const float4*)rw;
  float s = 0.f;
#pragma unroll
  for (int c = 0; c < 2; ++c) {
    float4 xv = x4[t + c * 256], wv = w4[t + c * 256];
    s += xv.x * wv.x + xv.y * wv.y + xv.z * wv.z + xv.w * wv.w;
  }
  for (int o = 32; o; o >>= 1) s += __shfl_down(s, o);
  __shared__ float red[4];
  if ((t & 63) == 0) red[t >> 6] = s;
  __syncthreads();
  if (t == 0) scores[b] = red[0] + red[1] + red[2] + red[3] + rb[0];
}

// ---------------- K2: exact top-k, deterministic (rank == slot) ----------------
__global__ void k_select(const float* __restrict__ scores, const int* __restrict__ kptr,
                         int* __restrict__ sel, int* __restrict__ pos) {
  __shared__ float sv[NROWS];
  int t = threadIdx.x;
  sv[t] = scores[t];
  __syncthreads();
  float s = sv[t];
  int c = 0;
  for (int j = 0; j < NROWS; ++j) {
    float o = sv[j];
    c += (o > s) || (o == s && j < t);
  }
  int k = *kptr;                 // k_sel == 128 (grids sized for it)
  if (c < k) sel[c] = t;
  pos[t] = (c < k) ? c : -1;
}

// ---------------- K3: rms1, init V=bv, X1=x, H bf16 ----------------
__global__ void k_rms1(const float* __restrict__ hid, const int* __restrict__ sel,
                       const float* __restrict__ ln1, const float* __restrict__ bv,
                       unsigned short* __restrict__ Hb, float* __restrict__ V,
                       float* __restrict__ X1) {
  int i = blockIdx.x, t = threadIdx.x;
  int r = sel[i];
  const float4* x4 = (const float4*)(hid + (size_t)r * D_);
  float4 xa = x4[2 * t], xb = x4[2 * t + 1];
  float ss = xa.x * xa.x + xa.y * xa.y + xa.z * xa.z + xa.w * xa.w
           + xb.x * xb.x + xb.y * xb.y + xb.z * xb.z + xb.w * xb.w;
  for (int o = 32; o; o >>= 1) ss += __shfl_down(ss, o);
  __shared__ float red[4];
  if ((t & 63) == 0) red[t >> 6] = ss;
  __syncthreads();
  float inv = rsqrtf((red[0] + red[1] + red[2] + red[3]) * (1.0f / D_) + 1e-6f);
  const float4* w4 = (const float4*)ln1;
  float4 wa = w4[2 * t], wb = w4[2 * t + 1];
  union { unsigned int u[4]; uint4 q; } pk;
  pk.u[0] = pk2(xa.x * inv * wa.x, xa.y * inv * wa.y);
  pk.u[1] = pk2(xa.z * inv * wa.z, xa.w * inv * wa.w);
  pk.u[2] = pk2(xb.x * inv * wb.x, xb.y * inv * wb.y);
  pk.u[3] = pk2(xb.z * inv * wb.z, xb.w * inv * wb.w);
  ((uint4*)(Hb + (size_t)i * D_))[t] = pk.q;
  const float4* b4 = (const float4*)bv;
  float4* V4 = (float4*)(V + (size_t)i * D_);
  V4[2 * t] = b4[2 * t]; V4[2 * t + 1] = b4[2 * t + 1];
  float4* X4 = (float4*)(X1 + (size_t)i * D_);
  X4[2 * t] = xa; X4[2 * t + 1] = xb;
}

// ---------------- K5: rms2 (G/U zeroing in k_zero) ----------------
__global__ void k_rms2(const float* __restrict__ X1, const float* __restrict__ ln2,
                       unsigned short* __restrict__ H2b) {
  int i = blockIdx.x, t = threadIdx.x;
  const float4* x4 = (const float4*)(X1 + (size_t)i * D_);
  float4 xa = x4[2 * t], xb = x4[2 * t + 1];
  float ss = xa.x * xa.x + xa.y * xa.y + xa.z * xa.z + xa.w * xa.w
           + xb.x * xb.x + xb.y * xb.y + xb.z * xb.z + xb.w * xb.w;
  for (int o = 32; o; o >>= 1) ss += __shfl_down(ss, o);
  __shared__ float red[4];
  if ((t & 63) == 0) red[t >> 6] = ss;
  __syncthreads();
  float inv = rsqrtf((red[0] + red[1] + red[2] + red[3]) * (1.0f / D_) + 1e-6f);
  const float4* w4 = (const float4*)ln2;
  float4 wa = w4[2 * t], wb = w4[2 * t + 1];
  union { unsigned int u[4]; uint4 q; } pk;
  pk.u[0] = pk2(xa.x * inv * wa.x, xa.y * inv * wa.y);
  pk.u[1] = pk2(xa.z * inv * wa.z, xa.w * inv * wa.w);
  pk.u[2] = pk2(xb.x * inv * wb.x, xb.y * inv * wb.y);
  pk.u[3] = pk2(xb.z * inv * wb.z, xb.w * inv * wb.w);
  ((uint4*)(H2b + (size_t)i * D_))[t] = pk.q;
}

// ---------------- K7: Mb = silu(G)*U ; out = copy/scatter ----------------
__global__ void k_silu_out(const float* __restrict__ G, const float* __restrict__ U,
                           unsigned short* __restrict__ Mb,
                           const float* __restrict__ X1, const int* __restrict__ pos,
                           const float* __restrict__ hid, float* __restrict__ out) {
  int tid = blockIdx.x * 256 + threadIdx.x;
  const int nM4 = KSEL * I_ / 4;    // 176128
  if (tid < nM4) {
    float4 g = ((const float4*)G)[tid], u = ((const float4*)U)[tid];
    float m0 = (g.x / (1.f + expf(-g.x))) * u.x;
    float m1 = (g.y / (1.f + expf(-g.y))) * u.y;
    float m2 = (g.z / (1.f + expf(-g.z))) * u.z;
    float m3 = (g.w / (1.f + expf(-g.w))) * u.w;
    uint2 o; o.x = pk2(m0, m1); o.y = pk2(m2, m3);
    ((uint2*)Mb)[tid] = o;
  }
  const int nO4 = NROWS * (D_ / 4);   // 131072 float4
  if (tid < nO4) {
    int row = tid >> 9;             // 512 float4 per row
    int c4 = tid & 511;
    int p = pos[row];
    ((float4*)out)[tid] = (p >= 0) ? ((const float4*)X1)[(size_t)p * 512 + c4]
                                   : ((const float4*)hid)[tid];
  }
}

// ---------------- GEMM: C[128xNN] += A[128xKA] @ B[KbxNN] ----------------
// Tile 64(M)x128(N), BK=32. 4 waves = 2 wm x 2 wn; wave = 32m x 64n
// (2 m-frags x 4 n-frags, acc 8 x floatx4). Block index -> (bm, bn, ks):
// bm in {0,1} selects A-row half; split-K over KT chunks, fp32 atomics.
// B staging: thread = one B column (bc = tid&127, k-half = (tid>>7)*16):
// one load instruction = 64 lanes x 4B consecutive = 256B contiguous (the
// granule fix). LDS [n][k] (ST=40 elems, 80B rows: stride/16B odd
// -> b128 phases spread over all banks). Depth-2 register prefetch + raw
// s_barrier + counted vmcnt (round-3 structure).
template<bool AF32, int NN>
__global__ __launch_bounds__(256, 4)
void k_gemm(const void* __restrict__ Ap, const float* __restrict__ B0,
            float* __restrict__ C0, const int* __restrict__ rowmap,
            int KA, int Kb, int lda, int ldc, int KT, int NT) {
  constexpr int ST = 40;   // LDS k-stride (elems): 80 B rows
  // bijective XCD-chunked swizzle (m204): consecutive nid share an XCD.
  const int nwg = gridDim.x, id = blockIdx.x;
  const int q = nwg >> 3, r8 = nwg & 7, xcd = id & 7, lid = id >> 3;
  const int nid = (xcd < r8 ? xcd * (q + 1) : r8 * (q + 1) + (xcd - r8) * q) + lid;
  const int bm = nid & 1;
  const int rest = nid >> 1;
  const int bn = rest % NT;
  const int ks = rest / NT;
  const int kt0 = ks * KT;
  const int kt1 = kt0 + KT;

  const int tid = threadIdx.x;
  const int lane = tid & 63;
  const int wave = tid >> 6;
  const int wm = wave >> 1, wn = wave & 1;
  const int fm = lane & 15, kq = lane >> 4;

  __shared__ alignas(16) unsigned short Asm[64 * ST];    // 5 KB
  __shared__ alignas(16) unsigned short Bsm[128 * ST];   // 10 KB

  floatx4 acc[2][4] = {};

  // A staging: thread -> row ar = tid>>2 (64 rows), col-granule (tid&3)*8
  const int ar = tid >> 2;
  const int acg = (tid & 3) * 8;
  // B staging: thread -> col bc = tid&127, k-half bkh = (tid>>7)*16
  const int bc = tid & 127;
  const int bkh = (tid >> 7) * 16;

  const unsigned short* Ab = AF32 ? nullptr
      : (const unsigned short*)Ap + (size_t)(bm * 64 + ar) * lda + acg;
  const float* Af = AF32 ? (const float*)Ap + (size_t)(bm * 64 + ar) * lda + acg
                         : nullptr;
  int bcg = bn * 128 + bc; if (bcg > NN - 1) bcg = NN - 1;
  const float* Bc = B0 + bcg;

  struct Regs {
    uint4 a;            // bf16 A: 8 elems (16 B)
    float4 af[2];       // fp32 A: 8 elems
    float b[16];        // B column: 16 k-rows
  };

  auto load_tile = [&](Regs& R, int kt) {
    const int c0 = kt + acg;
    const bool ok = c0 < KA;
    if constexpr (AF32) {
      R.af[0] = ok ? *(const float4*)(Af + kt) : make_float4(0.f, 0.f, 0.f, 0.f);
      R.af[1] = ok ? *(const float4*)(Af + kt + 4) : make_float4(0.f, 0.f, 0.f, 0.f);
    } else {
      R.a = ok ? *(const uint4*)(Ab + kt) : make_uint4(0u, 0u, 0u, 0u);
    }
    if (kt + bkh + 15 < Kb) {      // wave-uniform fast path
      const float* bp = Bc + (size_t)(kt + bkh) * NN;
#pragma unroll
      for (int j = 0; j < 16; ++j) R.b[j] = bp[(size_t)j * NN];
    } else {
#pragma unroll
      for (int j = 0; j < 16; ++j) {
        int kr = kt + bkh + j; kr = kr < Kb ? kr : Kb - 1;
        R.b[j] = Bc[(size_t)kr * NN];
      }
    }
  };

  auto store_lds = [&](Regs& R) {
    if constexpr (AF32) {
      union { unsigned int u[4]; uint4 qq; } pk;
      pk.u[0] = pk2(R.af[0].x, R.af[0].y);
      pk.u[1] = pk2(R.af[0].z, R.af[0].w);
      pk.u[2] = pk2(R.af[1].x, R.af[1].y);
      pk.u[3] = pk2(R.af[1].z, R.af[1].w);
      *(uint4*)&Asm[ar * ST + acg] = pk.qq;
    } else {
      *(uint4*)&Asm[ar * ST + acg] = R.a;
    }
    union { unsigned int u[4]; uint4 qq; } p0, p1;
    p0.u[0] = pk2(R.b[0], R.b[1]);   p0.u[1] = pk2(R.b[2], R.b[3]);
    p0.u[2] = pk2(R.b[4], R.b[5]);   p0.u[3] = pk2(R.b[6], R.b[7]);
    p1.u[0] = pk2(R.b[8], R.b[9]);   p1.u[1] = pk2(R.b[10], R.b[11]);
    p1.u[2] = pk2(R.b[12], R.b[13]); p1.u[3] = pk2(R.b[14], R.b[15]);
    *(uint4*)&Bsm[bc * ST + bkh] = p0.qq;
    *(uint4*)&Bsm[bc * ST + bkh + 8] = p1.qq;
  };

  auto mfma_phase = [&]() {
    short8 af_[2], bf_[4];
#pragma unroll
    for (int i = 0; i < 2; ++i)
      af_[i] = *(const short8*)&Asm[(wm * 32 + i * 16 + fm) * ST + kq * 8];
#pragma unroll
    for (int n = 0; n < 4; ++n)
      bf_[n] = *(const short8*)&Bsm[(wn * 64 + n * 16 + fm) * ST + kq * 8];
#pragma unroll
    for (int i = 0; i < 2; ++i)
#pragma unroll
      for (int n = 0; n < 4; ++n)
        acc[i][n] = __builtin_amdgcn_mfma_f32_16x16x32_bf16(af_[i], bf_[n], acc[i][n], 0, 0, 0);
  };

  // One pipeline stage: consume R (tile kt), reissue R's loads for kt+64.
  auto stage = [&](Regs& R, int kt) {
    __builtin_amdgcn_s_barrier();          // previous tile's readers done
    __builtin_amdgcn_sched_barrier(0);
    store_lds(R);                           // counted vmcnt wait on R's loads
    if (kt + 64 < kt1) load_tile(R, kt + 64);   // reissue 2-ahead
    asm volatile("s_waitcnt lgkmcnt(0)" ::: "memory");  // LDS writes retired
    __builtin_amdgcn_s_barrier();          // tile visible to all waves
    __builtin_amdgcn_sched_barrier(0);
    mfma_phase();
    __builtin_amdgcn_sched_barrier(0);     // pin reads/MFMAs before next barrier
  };

  Regs ra, rb;
  load_tile(ra, kt0);
  load_tile(rb, kt0 + 32);

  int kt = kt0;
  while (true) {
    stage(ra, kt);
    kt += 32; if (kt >= kt1) break;
    stage(rb, kt);
    kt += 32; if (kt >= kt1) break;
  }

  // epilogue: atomic accumulate (C/D layout: col=lane&15, row=(lane>>4)*4+reg)
#pragma unroll
  for (int i = 0; i < 2; ++i) {
#pragma unroll
    for (int n = 0; n < 4; ++n) {
#pragma unroll
      for (int rr = 0; rr < 4; ++rr) {
        int rowl = bm * 64 + wm * 32 + i * 16 + kq * 4 + rr;
        size_t rbase = rowmap ? (size_t)rowmap[rowl] * ldc : (size_t)rowl * ldc;
        int col = bn * 128 + wn * 64 + n * 16 + fm;
        if (col < NN) atomicAdd(&C0[rbase + col], acc[i][n][rr]);
      }
    }
  }
}

extern "C" void kernel_launch(void* const* d_in, const int* in_sizes, int n_in,
                              void* d_out, int out_size, void* d_ws, size_t ws_size,
                              hipStream_t stream) {
  const float* hid = (const float*)d_in[0];
  const float* rw  = (const float*)d_in[3];
  const float* rb  = (const float*)d_in[4];
  const float* ln1 = (const float*)d_in[5];
  const float* ln2 = (const float*)d_in[6];
  const float* wv  = (const float*)d_in[11];
  const float* bv  = (const float*)d_in[12];
  const float* wo  = (const float*)d_in[13];
  const float* wg  = (const float*)d_in[14];
  const float* wu  = (const float*)d_in[15];
  const float* wd  = (const float*)d_in[16];
  const int*   kp  = (const int*)d_in[17];
  float* out = (float*)d_out;

  char* ws = (char*)d_ws;
  float*          scores = (float*)(ws + 0);                // 1 KB
  int*            sel    = (int*)(ws + 1024);               // 512 B
  int*            pos    = (int*)(ws + 1536);               // 1 KB
  unsigned short* Hb     = (unsigned short*)(ws + 4096);    // 512 KB
  float*          V      = (float*)(ws + 528384);           // 1 MB
  float*          X1     = (float*)(ws + 1576960);          // 1 MB
  unsigned short* H2b    = (unsigned short*)(ws + 2625536); // 512 KB
  float*          G      = (float*)(ws + 3149824);          // 2.69 MB
  float*          U      = (float*)(ws + 5967872);          // 2.69 MB (contiguous with G)
  unsigned short* Mb     = (unsigned short*)(ws + 8785920); // 1.34 MB

  // zero G,U first (no deps; G..U contiguous 5636096 B = 352256 float4)
  k_zero<<<1024, 256, 0, stream>>>((float4*)G, 352256);
  k_router<<<256, 256, 0, stream>>>(hid, rw, rb, scores);
  k_select<<<1, 256, 0, stream>>>(scores, kp, sel, pos);
  k_rms1<<<128, 256, 0, stream>>>(hid, sel, ln1, bv, Hb, V, X1);
  // V += Hb @ wv   (16n x 2m x 16 splits = 512 blocks, KT=128: 4 stages)
  k_gemm<false, 2048><<<512, 256, 0, stream>>>(
      Hb, wv, V, nullptr, 2048, 2048, 2048, 2048, 128, 16);
  // X1 += V @ wo  (A fp32)
  k_gemm<true, 2048><<<512, 256, 0, stream>>>(
      V, wo, X1, nullptr, 2048, 2048, 2048, 2048, 128, 16);
  k_rms2<<<128, 256, 0, stream>>>(X1, ln2, H2b);
  // G += H2b @ wg   (43n x 2m x 6 splits = 516 blocks, KT=352: 11 stages)
  k_gemm<false, 5504><<<516, 256, 0, stream>>>(
      H2b, wg, G, nullptr, 2048, 2048, 2048, 5504, 352, 43);
  // U += H2b @ wu
  k_gemm<false, 5504><<<516, 256, 0, stream>>>(
      H2b, wu, U, nullptr, 2048, 2048, 2048, 5504, 352, 43);
  k_silu_out<<<1024, 256, 0, stream>>>(G, U, Mb, X1, pos, hid, out);
  // out[sel] += Mb @ wd  (16n x 2m x 16 splits = 512 blocks, KT=352: 11 stages)
  k_gemm<false, 2048><<<512, 256, 0, stream>>>(
      Mb, wd, out, sel, 5504, 5504, 5504, 2048, 352, 16);
}